// Round 15
// baseline (163.132 us; speedup 1.0000x reference)
//
#include <hip/hip_runtime.h>

namespace {

constexpr int NNODES = 50000;
constexpr int NEDGES = 800000;
constexpr int NBUCK  = (NNODES + 127) / 128;  // 391 buckets of 128 dst nodes
constexpr int BCAP   = 3072;                  // bucket capacity: mean 2048, ~22 sigma slack
constexpr int SB     = 64;                    // scatter/hist blocks
constexpr int CHUNK  = NEDGES / SB;           // 12500 edges per block (exact)
constexpr int CONVB  = 1024;                  // bf16-convert blocks (in histconv)

// ROUND-6: per-address global atomic ~140ns serialized -> never >1K ops/address.
// ROUND-7: aggregation must be node-parallel (50K waves), never bucket-parallel.
// ROUND-9: seg_mean is latency/issue-bound, not byte-bound.
// ROUND-11: grid-barrier mega-fusion caps phases at launch grid -> REGRESSED.
// ROUND-12: fusing the two GEMMs into one block starved the pipeline. Keep split.
// ROUND-14: GEMMs are fp32-FMA-issue-bound (21us compute floor) -> ROUND-15:
// move them to MFMA bf16 (2.5PF) with split-W (Whi+Wlo) to keep fp32-grade
// weight precision. A/B/D fragment maps per guide m89: A row=l&15,k=8*(l>>4)+j;
// B col=l&15 same k; D col=l&15,row=4*(l>>4)+e.

typedef __attribute__((ext_vector_type(8))) short bf16x8;
typedef __attribute__((ext_vector_type(4))) float f32x4;

static __device__ __forceinline__ unsigned short f2bf(float f) {
  unsigned u = __float_as_uint(f);
  u += 0x7FFFu + ((u >> 16) & 1u);   // round-to-nearest-even
  return (unsigned short)(u >> 16);
}
static __device__ __forceinline__ float bf2f(unsigned short b) {
  return __uint_as_float((unsigned)b << 16);
}

// In-block int64/int32 detection: odd 32-bit words of the first 4KB are the
// hi-halves of src values (< 50000) for int64 -> all zero; for int32 random.
static __device__ __forceinline__ int detect_is64_block(const void* raw, int* s_tmp) {
  if (threadIdx.x == 0) *s_tmp = 0;
  __syncthreads();
  const unsigned int* w = (const unsigned int*)raw;
  const int nz = (w[1 + 2 * (int)(threadIdx.x & 511)] != 0u) ? 1 : 0;
  if (nz) atomicOr(s_tmp, 1);
  __syncthreads();
  return (*s_tmp == 0) ? 1 : 0;
}

// ---------------------------------------------------------------------------
// Fused launch of three INDEPENDENT jobs (no barrier needed):
//   blocks [0, SB)            : per-block LDS histogram of dst buckets
//   blocks [SB, SB+CONVB)     : x -> bf16 convert (grid-strided)
//   blocks [SB+CONVB, +4)     : W -> transposed bf16 split (hi + lo residual)
__global__ __launch_bounds__(512) void histconv(const void* __restrict__ raw,
                                                const float* __restrict__ xin,
                                                const float* __restrict__ Wl1,
                                                const float* __restrict__ Wr1,
                                                const float* __restrict__ Wl2,
                                                const float* __restrict__ Wr2,
                                                unsigned short* __restrict__ xb,
                                                unsigned short* __restrict__ WT1hi,
                                                unsigned short* __restrict__ WT1lo,
                                                unsigned short* __restrict__ WT2hi,
                                                unsigned short* __restrict__ WT2lo,
                                                int* __restrict__ blkhist) {
  const int tid = (int)threadIdx.x;
  if (blockIdx.x >= SB + CONVB) {
    // W-prep: WT[j][k] = W[k][j] as bf16 hi + residual lo (split-W: weight
    // precision ~ fp32 when both MFMA'd into the same accumulator).
    const int q = (int)blockIdx.x - (SB + CONVB);   // 0..3
    const int layer = q >> 1;
    const int jbase = (q & 1) * 64;
    unsigned short* WH = layer ? WT2hi : WT1hi;
    unsigned short* WL = layer ? WT2lo : WT1lo;
    for (int t = tid; t < 64 * 128; t += 512) {
      const int j = jbase + (t >> 7);
      const int k = t & 127;
      float wv;
      if (layer == 0) wv = (k < 64) ? Wl1[(size_t)k * 128 + j]
                                    : Wr1[(size_t)(k - 64) * 128 + j];
      else            wv = (j < 64) ? Wl2[(size_t)k * 64 + j]
                                    : Wr2[(size_t)k * 64 + (j - 64)];
      const unsigned short hi = f2bf(wv);
      const unsigned short lo = f2bf(wv - bf2f(hi));
      WH[(size_t)j * 128 + k] = hi;
      WL[(size_t)j * 128 + k] = lo;
    }
    return;
  }
  if (blockIdx.x >= SB) {
    const int b = blockIdx.x - SB;
    for (int t = b * 512 + tid; t < NNODES * 64 / 4; t += CONVB * 512) {
      const float4 v = ((const float4*)xin)[t];
      ushort4 o;
      o.x = f2bf(v.x); o.y = f2bf(v.y); o.z = f2bf(v.z); o.w = f2bf(v.w);
      ((ushort4*)xb)[t] = o;
    }
    return;
  }
  __shared__ int hist[NBUCK];
  __shared__ int s_tmp;
  const int is64 = detect_is64_block(raw, &s_tmp);
  for (int i = tid; i < NBUCK; i += 512) hist[i] = 0;
  __syncthreads();
  const int b = blockIdx.x;
  const int beg = b * CHUNK, end = beg + CHUNK;
  for (int e = beg + tid; e < end; e += 512) {
    const int d = is64 ? (int)((const long long*)raw)[NEDGES + e]
                       : ((const int*)raw)[NEDGES + e];
    atomicAdd(&hist[d >> 7], 1);
  }
  __syncthreads();
  for (int i = tid; i < NBUCK; i += 512) blkhist[i * SB + b] = hist[i];
}

// Bucketed scatter; each block computes ITS OWN bucket offsets from blkhist.
// LDS cursors only, zero global atomics.
__global__ __launch_bounds__(512) void scatter_pass(const void* __restrict__ raw,
                                                    const int* __restrict__ blkhist,
                                                    unsigned int* __restrict__ ecol) {
  __shared__ int loff[NBUCK];
  __shared__ int lcur[NBUCK];
  __shared__ int s_tmp;
  const int is64 = detect_is64_block(raw, &s_tmp);
  const int b = blockIdx.x;
  const int tid = (int)threadIdx.x;
  for (int bk = tid; bk < NBUCK; bk += 512) {
    int s = 0;
    for (int bb = 0; bb < b; ++bb) s += blkhist[bk * SB + bb];
    loff[bk] = bk * BCAP + s;
    lcur[bk] = 0;
  }
  __syncthreads();
  const int beg = b * CHUNK, end = beg + CHUNK;
  for (int e = beg + tid; e < end; e += 512) {
    int s, d;
    if (is64) {
      const long long* p = (const long long*)raw;
      s = (int)p[e];
      d = (int)p[NEDGES + e];
    } else {
      const int* p = (const int*)raw;
      s = p[e];
      d = p[NEDGES + e];
    }
    const int bk = d >> 7;
    const unsigned int val = ((unsigned int)d << 16) | (unsigned int)s;
    const int lr = atomicAdd(&lcur[bk], 1);
    ecol[loff[bk] + lr] = val;
  }
}

// One block per bucket: in-place counting sort of packed edges to CSR order;
// emits packed rowse[v] = csr_start(bucket-padded) << 9 | deg.
__global__ __launch_bounds__(256) void csr_emit(const int* __restrict__ blkhist,
                                                unsigned int* __restrict__ ecol,
                                                int* __restrict__ rowse) {
  const int bk = blockIdx.x;
  const int base = bk * 128;
  const int nloc = min(128, NNODES - base);
  const int tid = (int)threadIdx.x;
  unsigned int* eb = ecol + (size_t)bk * BCAP;

  __shared__ int dcnt[128];
  __shared__ int noff[128];
  __shared__ int ncur[128];
  __shared__ int s_cnt;
  if (tid < 64) {
    int c = blkhist[bk * SB + tid];
#pragma unroll
    for (int off = 32; off; off >>= 1) c += __shfl_down(c, off, 64);
    if (tid == 0) s_cnt = c;
  }
  if (tid < 128) dcnt[tid] = 0;
  __syncthreads();
  const int cnt = s_cnt;               // <= BCAP = 3072 = 12*256

  unsigned int vals[12];
  int m = 0;
#pragma unroll
  for (int k = 0; k < 12; ++k) {
    const int e = tid + k * 256;
    if (e < cnt) {
      vals[k] = eb[e];
      atomicAdd(&dcnt[(vals[k] >> 16) & 127u], 1);
      m = k + 1;
    }
  }
  __syncthreads();

  if (tid < 128) noff[tid] = dcnt[tid];
  __syncthreads();
#pragma unroll
  for (int off = 1; off < 128; off <<= 1) {
    int add = 0;
    if (tid < 128 && tid >= off) add = noff[tid - off];
    __syncthreads();
    if (tid < 128) noff[tid] += add;
    __syncthreads();
  }
  if (tid < 128) {
    const int excl = noff[tid] - dcnt[tid];
    noff[tid] = excl;
    ncur[tid] = 0;
    if (tid < nloc)
      rowse[base + tid] = ((bk * BCAP + excl) << 9) | dcnt[tid];
  }
  __syncthreads();

#pragma unroll
  for (int k = 0; k < 12; ++k) {
    if (k < m) {
      const int loc = (int)((vals[k] >> 16) & 127u);
      eb[noff[loc] + atomicAdd(&ncur[loc], 1)] = vals[k] & 0xFFFFu;
    }
  }
}

// Segment mean, 2 edges per load instruction. rowse[v] = start<<9 | deg.
// FINAL=false: writes packed-bf16 pairs (mean operand for MFMA GEMM).
// FINAL=true : writes fp32 out + bf16 radd.
template <bool FINAL>
__global__ __launch_bounds__(256) void seg_mean_bf(const unsigned int* __restrict__ xb2,
                                                   const int* __restrict__ rowse,
                                                   const unsigned int* __restrict__ col,
                                                   const unsigned int* __restrict__ radd2,
                                                   float* __restrict__ outf,
                                                   unsigned int* __restrict__ outb) {
  const int lane = (int)(threadIdx.x & 63);
  const int half = lane >> 5;     // edge slot (0: even edges, 1: odd)
  const int c = lane & 31;        // channel pair (chans 2c, 2c+1)
  const int wid = (blockIdx.x * blockDim.x + threadIdx.x) >> 6;
  const int nw = (gridDim.x * blockDim.x) >> 6;
  for (int v = wid; v < NNODES; v += nw) {
    const int se = rowse[v];
    const int b = se >> 9;
    const int e = b + (se & 511);
    float accx = 0.0f, accy = 0.0f;
    int i = b;
    for (; i + 8 <= e; i += 8) {  // 8 edges via 4 dual-edge gathers in flight
      const int s0 = (int)col[i + 0 + half];
      const int s1 = (int)col[i + 2 + half];
      const int s2 = (int)col[i + 4 + half];
      const int s3 = (int)col[i + 6 + half];
      const unsigned int w0 = xb2[(size_t)s0 * 32 + c];
      const unsigned int w1 = xb2[(size_t)s1 * 32 + c];
      const unsigned int w2 = xb2[(size_t)s2 * 32 + c];
      const unsigned int w3 = xb2[(size_t)s3 * 32 + c];
      accx += __uint_as_float(w0 << 16) + __uint_as_float(w1 << 16)
            + __uint_as_float(w2 << 16) + __uint_as_float(w3 << 16);
      accy += __uint_as_float(w0 & 0xFFFF0000u) + __uint_as_float(w1 & 0xFFFF0000u)
            + __uint_as_float(w2 & 0xFFFF0000u) + __uint_as_float(w3 & 0xFFFF0000u);
    }
    for (; i + 2 <= e; i += 2) {  // pair remainder
      const unsigned int w0 = xb2[(size_t)col[i + half] * 32 + c];
      accx += __uint_as_float(w0 << 16);
      accy += __uint_as_float(w0 & 0xFFFF0000u);
    }
    if (i < e && half == 0) {     // odd last edge: slot 0 only
      const unsigned int w0 = xb2[(size_t)col[i] * 32 + c];
      accx += __uint_as_float(w0 << 16);
      accy += __uint_as_float(w0 & 0xFFFF0000u);
    }
    accx += __shfl_xor(accx, 32, 64);
    accy += __shfl_xor(accy, 32, 64);
    if (half == 0) {
      const float inv = 1.0f / fmaxf((float)(se & 511), 1.0f);
      float2 res = make_float2(accx * inv, accy * inv);
      const size_t gi = (size_t)v * 32 + c;
      if (FINAL) {
        const unsigned int ra = radd2[gi];   // 2 bf16 channels
        res.x += __uint_as_float(ra << 16);
        res.y += __uint_as_float(ra & 0xFFFF0000u);
        ((float2*)outf)[gi] = res;
      } else {
        outb[gi] = ((unsigned)f2bf(res.y) << 16) | (unsigned)f2bf(res.x);
      }
    }
  }
}

// ---------------------------------------------------------------------------
// MFMA bf16 GEMM (split-W): C[50000 x 128] = A[50000 x 128]bf16 @ W[128 x 128].
// Per 64-row block, 4 waves; wave w owns rows w*16..+15 x all 128 cols.
// W read fragment-direct from global WT (L2-hot, transposed bf16 hi+lo).
// MODE 0: A = [mb | xb], out = relu(C + bl1) -> HB[N,128] bf16
// MODE 1: A = hb,        out cols 0-63 -> PB (p), cols 64-127 + bl2 -> RB (r)
// ROUND-4 LESSON: #pragma unroll 1 on the ct loop (VGPR blowout -> spill).
template <int MODE>
__global__ __launch_bounds__(256, 4) void gemm_mfma(const unsigned short* __restrict__ A0,
                                                    const unsigned short* __restrict__ A1,
                                                    const unsigned short* __restrict__ WThi,
                                                    const unsigned short* __restrict__ WTlo,
                                                    const float* __restrict__ bias,
                                                    unsigned short* __restrict__ O0,
                                                    unsigned short* __restrict__ O1) {
  constexpr int LDA = 136;  // u16 A-tile stride: 272B = 68 dw = 4 mod 32 -> 2-way free
  constexpr int LDO = 132;  // u16 out stride: 264B = 66 dw = 2 mod 32 -> conflict-free
  __shared__ unsigned short At[64 * LDA];   // 17.4 KB (reused for epilogue at LDO)
  const int row0 = blockIdx.x * 64;
  const int tid = (int)threadIdx.x;

  // --- stage A tile: 64 rows x 128 bf16, coalesced ushort8 chunks ---
#pragma unroll
  for (int cc = 0; cc < 4; ++cc) {
    const int chunk = cc * 256 + tid;        // 0..1023
    const int rr = chunk >> 4;               // 0..63
    const int seg = chunk & 15;              // 16B segment
    const int grow = row0 + rr;
    ushort4 v0 = make_ushort4(0, 0, 0, 0), v1 = make_ushort4(0, 0, 0, 0);
    if (grow < NNODES) {
      const unsigned short* src;
      if (MODE == 0)
        src = (seg < 8) ? &A0[(size_t)grow * 64 + seg * 8]
                        : &A1[(size_t)grow * 64 + (seg - 8) * 8];
      else
        src = &A0[(size_t)grow * 128 + seg * 8];
      v0 = *(const ushort4*)src;
      v1 = *(const ushort4*)(src + 4);
    }
    *(ushort4*)&At[rr * LDA + seg * 8] = v0;
    *(ushort4*)&At[rr * LDA + seg * 8 + 4] = v1;
  }
  __syncthreads();

  const int w = tid >> 6;       // wave -> rows w*16..
  const int l = tid & 63;
  const int i16 = l & 15;
  const int g = l >> 4;         // k-group 0..3

  // A fragments for the 4 K-steps (preload BEFORE epilogue reuses At)
  bf16x8 af[4];
#pragma unroll
  for (int ks = 0; ks < 4; ++ks)
    af[ks] = *(const bf16x8*)&At[(w * 16 + i16) * LDA + ks * 32 + g * 8];
  __syncthreads();   // all waves' af loaded before anyone overwrites At

  // --- per col-tile: 4 K-steps x (hi + lo) MFMA, epilogue to LDS ---
#pragma unroll 1
  for (int ct = 0; ct < 8; ++ct) {
    f32x4 acc = {0.f, 0.f, 0.f, 0.f};
    const size_t wb = (size_t)(ct * 16 + i16) * 128 + g * 8;
#pragma unroll
    for (int ks = 0; ks < 4; ++ks) {
      const bf16x8 bh = *(const bf16x8*)&WThi[wb + ks * 32];
      acc = __builtin_amdgcn_mfma_f32_16x16x32_bf16(af[ks], bh, acc, 0, 0, 0);
      const bf16x8 bl = *(const bf16x8*)&WTlo[wb + ks * 32];
      acc = __builtin_amdgcn_mfma_f32_16x16x32_bf16(af[ks], bl, acc, 0, 0, 0);
    }
    const int colc = ct * 16 + i16;          // D: col = lane&15 (m89)
    float bsc = 0.f;
    if (MODE == 0) bsc = bias[colc];
    else if (colc >= 64) bsc = bias[colc - 64];
#pragma unroll
    for (int e = 0; e < 4; ++e) {            // D: row = 4*(lane>>4)+e (m89)
      float v = acc[e] + bsc;
      if (MODE == 0) v = fmaxf(v, 0.f);
      At[(w * 16 + g * 4 + e) * LDO + colc] = f2bf(v);
    }
  }
  __syncthreads();

  // --- coalesced bf16 store from LDS ---
#pragma unroll
  for (int cc = 0; cc < 4; ++cc) {
    const int chunk = cc * 256 + tid;
    const int rr = chunk >> 4;
    const int seg = chunk & 15;
    const int grow = row0 + rr;
    if (grow >= NNODES) continue;
    ushort4 v0 = *(const ushort4*)&At[rr * LDO + seg * 8];
    ushort4 v1 = *(const ushort4*)&At[rr * LDO + seg * 8 + 4];
    if (MODE == 0) {
      *(ushort4*)&O0[(size_t)grow * 128 + seg * 8] = v0;
      *(ushort4*)&O0[(size_t)grow * 128 + seg * 8 + 4] = v1;
    } else {
      unsigned short* dst = (seg < 8) ? &O0[(size_t)grow * 64 + seg * 8]
                                      : &O1[(size_t)grow * 64 + (seg - 8) * 8];
      *(ushort4*)dst = v0;
      *(ushort4*)(dst + 4) = v1;
    }
  }
}

}  // namespace

extern "C" void kernel_launch(void* const* d_in, const int* in_sizes, int n_in,
                              void* d_out, int out_size, void* d_ws, size_t ws_size,
                              hipStream_t stream) {
  const float* x   = (const float*)d_in[0];
  const void*  ei  = d_in[1];  // edge_index, int32 or int64 (detected in-block)
  const float* Wl1 = (const float*)d_in[2];
  const float* bl1 = (const float*)d_in[3];
  const float* Wr1 = (const float*)d_in[4];
  const float* Wl2 = (const float*)d_in[5];
  const float* bl2 = (const float*)d_in[6];
  const float* Wr2 = (const float*)d_in[7];
  float* out = (float*)d_out;

  // Workspace layout (bytes):
  //   blkhist [NBUCK*SB]   int32 @ 0          (100,352 padded)
  //   rowse   [N]          int32 @ 100,352    (200,704 padded)
  //   ecol    [NBUCK*BCAP] u32   @ 301,056    (4,804,608)
  //   xb      [N,64]       bf16  @ 5,105,664  (6,400,000)
  //   pb      [N,64]       bf16  @ 11,505,664 (6,400,000)
  //   mb      [N,64]       bf16  @ 17,905,664 (6,400,000)
  //   hb      [N,128]      bf16  @ 24,305,664 (12,800,000)
  //   rb      [N,64]       bf16  @ 37,105,664 (6,400,000)
  //   WT1hi/lo, WT2hi/lo [128][128] bf16 @ 43,505,664 (4 x 32,768)
  // total: 43,636,736 bytes. No memsets: every buffer fully written before read.
  char* ws = (char*)d_ws;
  int*            blkhist = (int*)(ws + 0);
  int*            rowse   = (int*)(ws + 100352);
  unsigned int*   ecol    = (unsigned int*)(ws + 301056);
  unsigned short* xb      = (unsigned short*)(ws + 5105664);
  unsigned short* pb      = (unsigned short*)(ws + 11505664);
  unsigned short* mb      = (unsigned short*)(ws + 17905664);
  unsigned short* hb      = (unsigned short*)(ws + 24305664);
  unsigned short* rb      = (unsigned short*)(ws + 37105664);
  unsigned short* WT1hi   = (unsigned short*)(ws + 43505664);
  unsigned short* WT1lo   = (unsigned short*)(ws + 43538432);
  unsigned short* WT2hi   = (unsigned short*)(ws + 43571200);
  unsigned short* WT2lo   = (unsigned short*)(ws + 43603968);

  // 7 dispatches: fused preprocessing + MFMA GEMMs + gathers.
  histconv<<<SB + CONVB + 4, 512, 0, stream>>>(ei, x, Wl1, Wr1, Wl2, Wr2,
                                               xb, WT1hi, WT1lo, WT2hi, WT2lo,
                                               blkhist);
  scatter_pass<<<SB, 512, 0, stream>>>(ei, blkhist, ecol);
  csr_emit<<<NBUCK, 256, 0, stream>>>(blkhist, ecol, rowse);

  constexpr int GEMM_BLOCKS = (NNODES + 63) / 64;  // 782

  seg_mean_bf<false><<<12500, 256, 0, stream>>>((const unsigned int*)xb, rowse, ecol,
                                                nullptr, nullptr, (unsigned int*)mb);
  gemm_mfma<0><<<GEMM_BLOCKS, 256, 0, stream>>>(mb, xb, WT1hi, WT1lo, bl1,
                                                hb, nullptr);
  gemm_mfma<1><<<GEMM_BLOCKS, 256, 0, stream>>>(hb, nullptr, WT2hi, WT2lo, bl2,
                                                pb, rb);
  seg_mean_bf<true><<<12500, 256, 0, stream>>>((const unsigned int*)pb, rowse, ecol,
                                               (const unsigned int*)rb, out, nullptr);
}

// Round 16
// 155.446 us; speedup vs baseline: 1.0494x; 1.0494x over previous
//
#include <hip/hip_runtime.h>

namespace {

constexpr int NNODES = 50000;
constexpr int NEDGES = 800000;
constexpr int NBUCK  = (NNODES + 127) / 128;  // 391 buckets of 128 dst nodes
constexpr int BCAP   = 3072;                  // bucket capacity: mean 2048, ~22 sigma slack
constexpr int SB     = 64;                    // scatter/hist blocks
constexpr int CHUNK  = NEDGES / SB;           // 12500 edges per block (exact)
constexpr int CONVB  = 1024;                  // bf16-convert blocks (in histconv)

// ROUND-6: per-address global atomic ~140ns serialized -> never >1K ops/address.
// ROUND-7: aggregation must be node-parallel (50K waves), never bucket-parallel.
// ROUND-9: seg_mean is latency/issue-bound, not byte-bound.
// ROUND-11: grid-barrier mega-fusion caps phases at launch grid -> REGRESSED.
// ROUND-12: fusing the two GEMMs into one block starved the pipeline. Keep split.
// ROUND-15: MFMA GEMM was flat (GEMMs already staging-bound, not FMA-bound).
// ROUND-16: seg_mean gathers 4 edges per load instruction (uint2/lane).

static __device__ __forceinline__ unsigned short f2bf(float f) {
  unsigned u = __float_as_uint(f);
  u += 0x7FFFu + ((u >> 16) & 1u);   // round-to-nearest-even
  return (unsigned short)(u >> 16);
}
static __device__ __forceinline__ float bf2f(unsigned short b) {
  return __uint_as_float((unsigned)b << 16);
}
static __device__ __forceinline__ float lo16(unsigned int w) {
  return __uint_as_float(w << 16);
}
static __device__ __forceinline__ float hi16(unsigned int w) {
  return __uint_as_float(w & 0xFFFF0000u);
}

// v_pk_fma_f32 with op_sel broadcast of one half of src0 (2 FMA/lane/cycle).
static __device__ __forceinline__ void pk_fma_lo(float2& d, const float2 a, const float2 b) {
  asm("v_pk_fma_f32 %0, %1, %2, %0 op_sel:[0,0,0] op_sel_hi:[0,1,1]"
      : "+v"(d) : "v"(a), "v"(b));
}
static __device__ __forceinline__ void pk_fma_hi(float2& d, const float2 a, const float2 b) {
  asm("v_pk_fma_f32 %0, %1, %2, %0 op_sel:[1,0,0] op_sel_hi:[1,1,1]"
      : "+v"(d) : "v"(a), "v"(b));
}

// In-block int64/int32 detection: odd 32-bit words of the first 4KB are the
// hi-halves of src values (< 50000) for int64 -> all zero; for int32 random.
static __device__ __forceinline__ int detect_is64_block(const void* raw, int* s_tmp) {
  if (threadIdx.x == 0) *s_tmp = 0;
  __syncthreads();
  const unsigned int* w = (const unsigned int*)raw;
  const int nz = (w[1 + 2 * (int)(threadIdx.x & 511)] != 0u) ? 1 : 0;
  if (nz) atomicOr(s_tmp, 1);
  __syncthreads();
  return (*s_tmp == 0) ? 1 : 0;
}

// ---------------------------------------------------------------------------
// Fused launch of two INDEPENDENT jobs (no barrier needed):
//   blocks 0..SB-1      : per-block LDS histogram of dst buckets
//   blocks SB..SB+CONVB : x -> bf16 convert (grid-strided)
__global__ __launch_bounds__(512) void histconv(const void* __restrict__ raw,
                                                const float* __restrict__ xin,
                                                unsigned short* __restrict__ xb,
                                                int* __restrict__ blkhist) {
  const int tid = (int)threadIdx.x;
  if (blockIdx.x >= SB) {
    const int b = blockIdx.x - SB;
    for (int t = b * 512 + tid; t < NNODES * 64 / 4; t += CONVB * 512) {
      const float4 v = ((const float4*)xin)[t];
      ushort4 o;
      o.x = f2bf(v.x); o.y = f2bf(v.y); o.z = f2bf(v.z); o.w = f2bf(v.w);
      ((ushort4*)xb)[t] = o;
    }
    return;
  }
  __shared__ int hist[NBUCK];
  __shared__ int s_tmp;
  const int is64 = detect_is64_block(raw, &s_tmp);
  for (int i = tid; i < NBUCK; i += 512) hist[i] = 0;
  __syncthreads();
  const int b = blockIdx.x;
  const int beg = b * CHUNK, end = beg + CHUNK;
  for (int e = beg + tid; e < end; e += 512) {
    const int d = is64 ? (int)((const long long*)raw)[NEDGES + e]
                       : ((const int*)raw)[NEDGES + e];
    atomicAdd(&hist[d >> 7], 1);
  }
  __syncthreads();
  for (int i = tid; i < NBUCK; i += 512) blkhist[i * SB + b] = hist[i];
}

// Bucketed scatter; each block computes ITS OWN bucket offsets from blkhist.
// LDS cursors only, zero global atomics.
__global__ __launch_bounds__(512) void scatter_pass(const void* __restrict__ raw,
                                                    const int* __restrict__ blkhist,
                                                    unsigned int* __restrict__ ecol) {
  __shared__ int loff[NBUCK];
  __shared__ int lcur[NBUCK];
  __shared__ int s_tmp;
  const int is64 = detect_is64_block(raw, &s_tmp);
  const int b = blockIdx.x;
  const int tid = (int)threadIdx.x;
  for (int bk = tid; bk < NBUCK; bk += 512) {
    int s = 0;
    for (int bb = 0; bb < b; ++bb) s += blkhist[bk * SB + bb];
    loff[bk] = bk * BCAP + s;
    lcur[bk] = 0;
  }
  __syncthreads();
  const int beg = b * CHUNK, end = beg + CHUNK;
  for (int e = beg + tid; e < end; e += 512) {
    int s, d;
    if (is64) {
      const long long* p = (const long long*)raw;
      s = (int)p[e];
      d = (int)p[NEDGES + e];
    } else {
      const int* p = (const int*)raw;
      s = p[e];
      d = p[NEDGES + e];
    }
    const int bk = d >> 7;
    const unsigned int val = ((unsigned int)d << 16) | (unsigned int)s;
    const int lr = atomicAdd(&lcur[bk], 1);
    ecol[loff[bk] + lr] = val;
  }
}

// One block per bucket: in-place counting sort of packed edges to CSR order;
// emits packed rowse[v] = csr_start(bucket-padded) << 9 | deg.
__global__ __launch_bounds__(256) void csr_emit(const int* __restrict__ blkhist,
                                                unsigned int* __restrict__ ecol,
                                                int* __restrict__ rowse) {
  const int bk = blockIdx.x;
  const int base = bk * 128;
  const int nloc = min(128, NNODES - base);
  const int tid = (int)threadIdx.x;
  unsigned int* eb = ecol + (size_t)bk * BCAP;

  __shared__ int dcnt[128];
  __shared__ int noff[128];
  __shared__ int ncur[128];
  __shared__ int s_cnt;
  if (tid < 64) {
    int c = blkhist[bk * SB + tid];
#pragma unroll
    for (int off = 32; off; off >>= 1) c += __shfl_down(c, off, 64);
    if (tid == 0) s_cnt = c;
  }
  if (tid < 128) dcnt[tid] = 0;
  __syncthreads();
  const int cnt = s_cnt;               // <= BCAP = 3072 = 12*256

  unsigned int vals[12];
  int m = 0;
#pragma unroll
  for (int k = 0; k < 12; ++k) {
    const int e = tid + k * 256;
    if (e < cnt) {
      vals[k] = eb[e];
      atomicAdd(&dcnt[(vals[k] >> 16) & 127u], 1);
      m = k + 1;
    }
  }
  __syncthreads();

  if (tid < 128) noff[tid] = dcnt[tid];
  __syncthreads();
#pragma unroll
  for (int off = 1; off < 128; off <<= 1) {
    int add = 0;
    if (tid < 128 && tid >= off) add = noff[tid - off];
    __syncthreads();
    if (tid < 128) noff[tid] += add;
    __syncthreads();
  }
  if (tid < 128) {
    const int excl = noff[tid] - dcnt[tid];
    noff[tid] = excl;
    ncur[tid] = 0;
    if (tid < nloc)
      rowse[base + tid] = ((bk * BCAP + excl) << 9) | dcnt[tid];
  }
  __syncthreads();

#pragma unroll
  for (int k = 0; k < 12; ++k) {
    if (k < m) {
      const int loc = (int)((vals[k] >> 16) & 127u);
      eb[noff[loc] + atomicAdd(&ncur[loc], 1)] = vals[k] & 0xFFFFu;
    }
  }
}

// Segment mean, 4 edges per load instruction: lane = (edge-slot 0..3,
// channel-quad 0..15). Each lane loads uint2 (8B = 4 bf16 channels); one
// 64-lane instruction gathers 4 full 128B rows. Cross-slot reduce via
// shfl_xor(16) + shfl_xor(32). rowse[v] = start<<9 | deg. fp32 accumulate.
// radd (FINAL) is bf16 [N,64].
template <bool FINAL>
__global__ __launch_bounds__(256) void seg_mean_bf(const uint2* __restrict__ xb2,
                                                   const int* __restrict__ rowse,
                                                   const unsigned int* __restrict__ col,
                                                   const uint2* __restrict__ radd2,
                                                   float* __restrict__ outbuf) {
  const int lane = (int)(threadIdx.x & 63);
  const int slot = lane >> 4;     // edge slot 0..3
  const int q = lane & 15;        // channel quad (chans 4q..4q+3)
  const int wid = (blockIdx.x * blockDim.x + threadIdx.x) >> 6;
  const int nw = (gridDim.x * blockDim.x) >> 6;
  for (int v = wid; v < NNODES; v += nw) {
    const int se = rowse[v];
    const int b = se >> 9;
    const int e = b + (se & 511);
    float ax = 0.f, ay = 0.f, az = 0.f, aw = 0.f;
    int i = b;
    for (; i + 16 <= e; i += 16) {  // 16 edges via 4 quad-edge gathers in flight
      const int s0 = (int)col[i + slot];
      const int s1 = (int)col[i + 4 + slot];
      const int s2 = (int)col[i + 8 + slot];
      const int s3 = (int)col[i + 12 + slot];
      const uint2 w0 = xb2[(size_t)s0 * 16 + q];
      const uint2 w1 = xb2[(size_t)s1 * 16 + q];
      const uint2 w2 = xb2[(size_t)s2 * 16 + q];
      const uint2 w3 = xb2[(size_t)s3 * 16 + q];
      ax += (lo16(w0.x) + lo16(w1.x)) + (lo16(w2.x) + lo16(w3.x));
      ay += (hi16(w0.x) + hi16(w1.x)) + (hi16(w2.x) + hi16(w3.x));
      az += (lo16(w0.y) + lo16(w1.y)) + (lo16(w2.y) + lo16(w3.y));
      aw += (hi16(w0.y) + hi16(w1.y)) + (hi16(w2.y) + hi16(w3.y));
    }
    for (; i + 4 <= e; i += 4) {    // quad remainder
      const uint2 w0 = xb2[(size_t)col[i + slot] * 16 + q];
      ax += lo16(w0.x); ay += hi16(w0.x);
      az += lo16(w0.y); aw += hi16(w0.y);
    }
    const int rem = e - i;          // 0..3
    if (slot < rem) {               // masked final partial quad
      const uint2 w0 = xb2[(size_t)col[i + slot] * 16 + q];
      ax += lo16(w0.x); ay += hi16(w0.x);
      az += lo16(w0.y); aw += hi16(w0.y);
    }
    // reduce across the 4 edge slots (xor 16 then 32)
    ax += __shfl_xor(ax, 16, 64); ay += __shfl_xor(ay, 16, 64);
    az += __shfl_xor(az, 16, 64); aw += __shfl_xor(aw, 16, 64);
    ax += __shfl_xor(ax, 32, 64); ay += __shfl_xor(ay, 32, 64);
    az += __shfl_xor(az, 32, 64); aw += __shfl_xor(aw, 32, 64);
    if (slot == 0) {
      const float inv = 1.0f / fmaxf((float)(se & 511), 1.0f);
      float4 res = make_float4(ax * inv, ay * inv, az * inv, aw * inv);
      if (FINAL) {
        const uint2 ra = radd2[(size_t)v * 16 + q];   // 4 bf16 channels
        res.x += lo16(ra.x); res.y += hi16(ra.x);
        res.z += lo16(ra.y); res.w += hi16(ra.y);
      }
      ((float4*)outbuf)[(size_t)v * 16 + q] = res;
    }
  }
}

// ---------------------------------------------------------------------------
// Register-tiled fp32 GEMM with v_pk_fma_f32 inner loop (split layers --
// round-12 lesson). h intermediate is bf16 (halves its round-trip traffic).
// MODE 0 (layer 1): A = [mean1 | x] (fp32), W = [Wl1 ; Wr1],
//                   HB[N,128](bf16) = relu(C + bias)
// MODE 1 (layer 2): A = HB (bf16), W = [Wl2 | Wr2],
//                   PB[N,64](bf16) = C[:,0:64] (p); RB[N,64](bf16) = C[:,64:] + bias
// ROUND-4 LESSON: do NOT unroll the outer ck loop (VGPR blowout -> spill).
template <int MODE>
__global__ __launch_bounds__(256, 4) void gemm128(const float* __restrict__ A0,
                                                  const float* __restrict__ A1,
                                                  const unsigned short* __restrict__ AH,
                                                  const float* __restrict__ W0,
                                                  const float* __restrict__ W1,
                                                  const float* __restrict__ bias,
                                                  unsigned short* __restrict__ HB,
                                                  unsigned short* __restrict__ PB,
                                                  unsigned short* __restrict__ RB) {
  constexpr int SAS = 36;  // sA row stride (pad 32->36: rows land on distinct banks)
  __shared__ float sA[64][SAS];
  __shared__ float sW[32][128];
  const int row0 = blockIdx.x * 64;
  const int tid = threadIdx.x;
  const int r0 = (tid >> 4) * 4;
  const int j0 = (tid & 15) * 4;

  float2 accA2[4][2];
  float2 accB2[4][2];
#pragma unroll
  for (int r = 0; r < 4; ++r)
#pragma unroll
    for (int p = 0; p < 2; ++p) {
      accA2[r][p] = make_float2(0.f, 0.f);
      accB2[r][p] = make_float2(0.f, 0.f);
    }

#pragma unroll 1   // keep ONE copy of the body (round-4 lesson)
  for (int ck = 0; ck < 4; ++ck) {
#pragma unroll
    for (int v = 0; v < 2; ++v) {
      const int vid = v * 256 + tid;
      const int rr = vid >> 3;
      const int kq = (vid & 7) * 4;
      const int grow = row0 + rr;
      float4 val = make_float4(0.f, 0.f, 0.f, 0.f);
      if (grow < NNODES) {
        if (MODE == 0) {
          const float* src = (ck < 2) ? A0 : A1;
          const int kk = (ck & 1) * 32 + kq;
          val = *(const float4*)&src[(size_t)grow * 64 + kk];
        } else {
          const ushort4 us = *(const ushort4*)&AH[(size_t)grow * 128 + ck * 32 + kq];
          val = make_float4(bf2f(us.x), bf2f(us.y), bf2f(us.z), bf2f(us.w));
        }
      }
      *(float4*)&sA[rr][kq] = val;
    }
#pragma unroll
    for (int v = 0; v < 4; ++v) {
      const int vid = v * 256 + tid;
      const int kk = vid >> 5;
      const int jq = (vid & 31) * 4;
      float4 w;
      if (MODE == 0) {
        const float* src = (ck < 2) ? W0 : W1;
        const int krel = (ck & 1) * 32 + kk;
        w = *(const float4*)&src[(size_t)krel * 128 + jq];
      } else {
        const int kg = ck * 32 + kk;
        const float* src = (jq < 64) ? W0 : W1;
        const int jrel = (jq < 64) ? jq : jq - 64;
        w = *(const float4*)&src[(size_t)kg * 64 + jrel];
      }
      *(float4*)&sW[kk][jq] = w;
    }
    __syncthreads();
#pragma unroll
    for (int k4 = 0; k4 < 8; ++k4) {
      float4 a[4];
#pragma unroll
      for (int r = 0; r < 4; ++r) a[r] = *(const float4*)&sA[r0 + r][k4 * 4];
#pragma unroll
      for (int kp = 0; kp < 2; ++kp) {
        const int k_even = k4 * 4 + kp * 2;
        const float4 wlo0 = *(const float4*)&sW[k_even][j0];
        const float4 whi0 = *(const float4*)&sW[k_even][64 + j0];
        const float4 wlo1 = *(const float4*)&sW[k_even + 1][j0];
        const float4 whi1 = *(const float4*)&sW[k_even + 1][64 + j0];
#pragma unroll
        for (int r = 0; r < 4; ++r) {
          const float2 ap = (kp == 0) ? make_float2(a[r].x, a[r].y)
                                      : make_float2(a[r].z, a[r].w);
          pk_fma_lo(accA2[r][0], ap, make_float2(wlo0.x, wlo0.y));
          pk_fma_lo(accA2[r][1], ap, make_float2(wlo0.z, wlo0.w));
          pk_fma_lo(accB2[r][0], ap, make_float2(whi0.x, whi0.y));
          pk_fma_lo(accB2[r][1], ap, make_float2(whi0.z, whi0.w));
          pk_fma_hi(accA2[r][0], ap, make_float2(wlo1.x, wlo1.y));
          pk_fma_hi(accA2[r][1], ap, make_float2(wlo1.z, wlo1.w));
          pk_fma_hi(accB2[r][0], ap, make_float2(whi1.x, whi1.y));
          pk_fma_hi(accB2[r][1], ap, make_float2(whi1.z, whi1.w));
        }
      }
    }
    __syncthreads();
  }

  // --- epilogue ---
  float4 blo = make_float4(0.f, 0.f, 0.f, 0.f);
  float4 bhi;
  if (MODE == 0) {
    blo = *(const float4*)&bias[j0];
    bhi = *(const float4*)&bias[64 + j0];
  } else {
    bhi = *(const float4*)&bias[j0];  // bias applies to r (upper half)
  }
#pragma unroll
  for (int r = 0; r < 4; ++r) {
    const int grow = row0 + r0 + r;
    if (grow >= NNODES) continue;
    float4 lo = make_float4(accA2[r][0].x + blo.x, accA2[r][0].y + blo.y,
                            accA2[r][1].x + blo.z, accA2[r][1].y + blo.w);
    float4 hi = make_float4(accB2[r][0].x + bhi.x, accB2[r][0].y + bhi.y,
                            accB2[r][1].x + bhi.z, accB2[r][1].y + bhi.w);
    if (MODE == 0) {
      ushort4 olo, ohi;
      olo.x = f2bf(fmaxf(lo.x, 0.f)); olo.y = f2bf(fmaxf(lo.y, 0.f));
      olo.z = f2bf(fmaxf(lo.z, 0.f)); olo.w = f2bf(fmaxf(lo.w, 0.f));
      ohi.x = f2bf(fmaxf(hi.x, 0.f)); ohi.y = f2bf(fmaxf(hi.y, 0.f));
      ohi.z = f2bf(fmaxf(hi.z, 0.f)); ohi.w = f2bf(fmaxf(hi.w, 0.f));
      *(ushort4*)&HB[(size_t)grow * 128 + j0] = olo;
      *(ushort4*)&HB[(size_t)grow * 128 + 64 + j0] = ohi;
    } else {
      ushort4 op, orr;
      op.x = f2bf(lo.x); op.y = f2bf(lo.y); op.z = f2bf(lo.z); op.w = f2bf(lo.w);
      orr.x = f2bf(hi.x); orr.y = f2bf(hi.y); orr.z = f2bf(hi.z); orr.w = f2bf(hi.w);
      *(ushort4*)&PB[(size_t)grow * 64 + j0] = op;   // p (gather operand)
      *(ushort4*)&RB[(size_t)grow * 64 + j0] = orr;  // r (+bl2)
    }
  }
}

}  // namespace

extern "C" void kernel_launch(void* const* d_in, const int* in_sizes, int n_in,
                              void* d_out, int out_size, void* d_ws, size_t ws_size,
                              hipStream_t stream) {
  const float* x   = (const float*)d_in[0];
  const void*  ei  = d_in[1];  // edge_index, int32 or int64 (detected in-block)
  const float* Wl1 = (const float*)d_in[2];
  const float* bl1 = (const float*)d_in[3];
  const float* Wr1 = (const float*)d_in[4];
  const float* Wl2 = (const float*)d_in[5];
  const float* bl2 = (const float*)d_in[6];
  const float* Wr2 = (const float*)d_in[7];
  float* out = (float*)d_out;

  // Workspace layout (bytes):
  //   blkhist [NBUCK*SB]   int32 @ 0          (100,352 padded)
  //   rowse   [N]          int32 @ 100,352    (200,704 padded)
  //   ecol    [NBUCK*BCAP] u32   @ 301,056    (4,804,608)  packed edges -> sorted src
  //   xb      [N,64]       bf16  @ 5,105,664  (6,400,000)
  //   pb      [N,64]       bf16  @ 11,505,664 (6,400,000)
  //   mean1   [N,64]       f32   @ 17,905,664 (12,800,000)
  //   hb      [N,128]      bf16  @ 30,705,664 (12,800,000)
  //   rb      [N,64]       bf16  @ 43,505,664 (6,400,000)
  // total: 49,905,664 bytes. No memsets: every buffer fully written before read.
  char* ws = (char*)d_ws;
  int*            blkhist = (int*)(ws + 0);
  int*            rowse   = (int*)(ws + 100352);
  unsigned int*   ecol    = (unsigned int*)(ws + 301056);
  unsigned short* xb      = (unsigned short*)(ws + 5105664);
  unsigned short* pb      = (unsigned short*)(ws + 11505664);
  float*          mean1   = (float*)(ws + 17905664);
  unsigned short* hb      = (unsigned short*)(ws + 30705664);
  unsigned short* rb      = (unsigned short*)(ws + 43505664);

  // 7 dispatches: round-12 preprocessing + round-14 GEMMs + quad-edge gathers.
  histconv<<<SB + CONVB, 512, 0, stream>>>(ei, x, xb, blkhist);
  scatter_pass<<<SB, 512, 0, stream>>>(ei, blkhist, ecol);
  csr_emit<<<NBUCK, 256, 0, stream>>>(blkhist, ecol, rowse);

  constexpr int GEMM_BLOCKS = (NNODES + 63) / 64;  // 782

  seg_mean_bf<false><<<12500, 256, 0, stream>>>((const uint2*)xb, rowse, ecol,
                                                nullptr, mean1);
  gemm128<0><<<GEMM_BLOCKS, 256, 0, stream>>>(mean1, x, nullptr, Wl1, Wr1, bl1,
                                              hb, nullptr, nullptr);
  gemm128<1><<<GEMM_BLOCKS, 256, 0, stream>>>(nullptr, nullptr, hb, Wl2, Wr2, bl2,
                                              nullptr, pb, rb);
  seg_mean_bf<true><<<12500, 256, 0, stream>>>((const uint2*)pb, rowse, ecol,
                                               (const uint2*)rb, out);
}